// Round 2
// baseline (15412.468 us; speedup 1.0000x reference)
//
#include <hip/hip_runtime.h>
#include <cstdio>
#include <cstddef>

enum { ACT_NONE = 0, ACT_LEAKY = 1, ACT_RELU = 2, ACT_ELU = 3 };

__device__ __forceinline__ float leakyf(float x) { return x > 0.f ? x : 0.01f * x; }

// order-preserving float -> uint encoding for atomicMax
__device__ __forceinline__ unsigned fenc(float f) {
    unsigned u = __float_as_uint(f);
    return (u & 0x80000000u) ? ~u : (u | 0x80000000u);
}
__device__ __forceinline__ float fdec(unsigned u) {
    return (u & 0x80000000u) ? __uint_as_float(u & 0x7FFFFFFFu) : __uint_as_float(~u);
}

// ---------------------------------------------------------------------------
// Tiled fp32 GEMM:  C[r][colBase+c] = actOut( A'[r][:] @ B + bias )
//   A' row r = concat( A[idx? idx[r] : r][0:K1], A2[r][0:K-K1] ), actIn applied.
//   B layout: BT ? [NCtot][K] row-major (weight.T usage) : [K][NCtot] row-major.
// Block: 256 threads, tile 64 rows x 128 cols, micro-tile 4x8, KT=16.
// In-place (C == A) is safe: single col-tile per row range, writes in epilogue.
// ---------------------------------------------------------------------------
template <bool BT>
__global__ __launch_bounds__(256, 2) void gemm_k(
    const float* __restrict__ A, const float* __restrict__ A2,
    const int* __restrict__ idx,
    const float* __restrict__ B, const float* __restrict__ bias,
    float* __restrict__ C,
    int M, int K, int K1, int NCtot, int actIn, int actOut)
{
    __shared__ float Xs[16][64];
    __shared__ float Ws[16][128];
    const int t  = threadIdx.x;
    const int tx = t & 15;   // col group: cols tx*8..+7
    const int ty = t >> 4;   // row group: rows ty*4..+3
    const int rowBase = blockIdx.x * 64;
    const int colBase = blockIdx.y * 128;

    float acc[4][8];
#pragma unroll
    for (int i = 0; i < 4; i++)
#pragma unroll
        for (int j = 0; j < 8; j++) acc[i][j] = 0.f;

    const int rS = t >> 2;          // staging row 0..63
    const int kS = (t & 3) << 2;    // staging k offset 0/4/8/12
    const int K2 = K - K1;

    for (int k0 = 0; k0 < K; k0 += 16) {
        // ---- stage A tile, transposed to Xs[k][row] ----
        {
            float v[4] = {0.f, 0.f, 0.f, 0.f};
            const int row = rowBase + rS;
            if (row < M) {
                const int arow = idx ? idx[row] : row;
                const float* __restrict__ a1 = A + (size_t)arow * K1;
#pragma unroll
                for (int j = 0; j < 4; j++) {
                    const int k = k0 + kS + j;
                    float x = 0.f;
                    if (k < K1)     x = a1[k];
                    else if (k < K) x = A2[(size_t)row * K2 + (k - K1)];
                    v[j] = x;
                }
                if (actIn == ACT_ELU) {
#pragma unroll
                    for (int j = 0; j < 4; j++) v[j] = v[j] > 0.f ? v[j] : expm1f(v[j]);
                }
            }
#pragma unroll
            for (int j = 0; j < 4; j++) Xs[kS + j][rS] = v[j];
        }
        // ---- stage B tile to Ws[k][col] ----
        if (!BT) {
#pragma unroll
            for (int p = 0; p < 2; p++) {
                const int kk = (t >> 5) + p * 8;
                const int cc = (t & 31) << 2;
                const int k  = k0 + kk;
                float4 wv = make_float4(0.f, 0.f, 0.f, 0.f);
                if (k < K) wv = *(const float4*)&B[(size_t)k * NCtot + colBase + cc];
                *(float4*)&Ws[kk][cc] = wv;
            }
        } else {
            const int cc   = t >> 1;
            const int koff = (t & 1) << 3;
            const float* __restrict__ bp = B + (size_t)(colBase + cc) * K + k0 + koff;
#pragma unroll
            for (int j = 0; j < 8; j++) {
                const int k = k0 + koff + j;
                Ws[koff + j][cc] = (k < K) ? bp[j] : 0.f;
            }
        }
        __syncthreads();
#pragma unroll
        for (int k = 0; k < 16; k++) {
            const float4 xv = *(const float4*)&Xs[k][ty << 2];
            const float4 wa = *(const float4*)&Ws[k][tx << 3];
            const float4 wb = *(const float4*)&Ws[k][(tx << 3) + 4];
            const float xs[4]  = {xv.x, xv.y, xv.z, xv.w};
            const float ws8[8] = {wa.x, wa.y, wa.z, wa.w, wb.x, wb.y, wb.z, wb.w};
#pragma unroll
            for (int i = 0; i < 4; i++)
#pragma unroll
                for (int j = 0; j < 8; j++)
                    acc[i][j] = fmaf(xs[i], ws8[j], acc[i][j]);
        }
        __syncthreads();
    }

#pragma unroll
    for (int i = 0; i < 4; i++) {
        const int row = rowBase + (ty << 2) + i;
        if (row >= M) continue;
        float o[8];
#pragma unroll
        for (int j = 0; j < 8; j++) {
            float v = acc[i][j] + bias[colBase + (tx << 3) + j];
            if (actOut == ACT_LEAKY)      v = v > 0.f ? v : 0.01f * v;
            else if (actOut == ACT_RELU)  v = fmaxf(v, 0.f);
            o[j] = v;
        }
        float* __restrict__ cp = C + (size_t)row * NCtot + colBase + (tx << 3);
        *(float4*)cp       = make_float4(o[0], o[1], o[2], o[3]);
        *(float4*)(cp + 4) = make_float4(o[4], o[5], o[6], o[7]);
    }
}

// ---------------------------------------------------------------------------
// per-node dual dot: pd[i] = h[i]·wa, ps[i] = h[i]·wb   (one wave per node)
// ---------------------------------------------------------------------------
__global__ __launch_bounds__(256) void node_dots_k(
    const float* __restrict__ h, const float* __restrict__ wa,
    const float* __restrict__ wb, float* __restrict__ pd, float* __restrict__ ps, int n)
{
    const int i = blockIdx.x * 4 + (threadIdx.x >> 6);
    const int l = threadIdx.x & 63;
    if (i >= n) return;
    const float2 hv = *(const float2*)&h[(size_t)i * 128 + l * 2];
    float a = hv.x * wa[l * 2] + hv.y * wa[l * 2 + 1];
    float b = 0.f;
    if (wb) b = hv.x * wb[l * 2] + hv.y * wb[l * 2 + 1];
#pragma unroll
    for (int o = 32; o; o >>= 1) {
        a += __shfl_down(a, o, 64);
        b += __shfl_down(b, o, 64);
    }
    if (l == 0) {
        pd[i] = a;
        if (ps) ps[i] = b;
    }
}

// GetContext edge logits from precomputed pe: lg = leaky(pd[dst]+pe[e]+b2); atomicMax m
__global__ __launch_bounds__(256) void edge_lgc_k(
    const float* __restrict__ pd, const float* __restrict__ pe,
    const float* __restrict__ b2, const int* __restrict__ dst,
    float* __restrict__ lg, unsigned* __restrict__ m_u, int E)
{
    const int e = blockIdx.x * blockDim.x + threadIdx.x;
    if (e >= E) return;
    const int d = dst[e];
    const float v = leakyf(pd[d] + pe[e] + b2[0]);
    lg[e] = v;
    atomicMax(&m_u[d], fenc(v));
}

// layer edge logits: lg = leaky(pd[dst] + ps[src] + bpe); atomicMax m
__global__ __launch_bounds__(256) void edge_lg_k(
    const float* __restrict__ pd, const float* __restrict__ ps,
    const float* __restrict__ bpe, const int* __restrict__ src,
    const int* __restrict__ dst, float* __restrict__ lg,
    unsigned* __restrict__ m_u, int E)
{
    const int e = blockIdx.x * blockDim.x + threadIdx.x;
    if (e >= E) return;
    const int d = dst[e];
    const float v = leakyf(pd[d] + ps[src[e]] + bpe[0]);
    lg[e] = v;
    atomicMax(&m_u[d], fenc(v));
}

// e = exp(lg - m[dst]); s[dst] += e
__global__ __launch_bounds__(256) void edge_exp_k(
    float* __restrict__ lg, const unsigned* __restrict__ m_u,
    float* __restrict__ s, const int* __restrict__ dst, int E)
{
    const int e = blockIdx.x * blockDim.x + threadIdx.x;
    if (e >= E) return;
    const int d = dst[e];
    const float ex = expf(lg[e] - fdec(m_u[d]));
    lg[e] = ex;
    atomicAdd(&s[d], ex);
}

// c[dst[e]] += (ee[e]/s[dst[e]]) * rows[ridx? ridx[e] : e]   (64 lanes x 2 cols)
__global__ __launch_bounds__(256) void scatter_c_k(
    const float* __restrict__ rows, const int* __restrict__ ridx,
    const float* __restrict__ ee, const float* __restrict__ s,
    const int* __restrict__ dst, float* __restrict__ c, int E)
{
    const long long gid = (long long)blockIdx.x * blockDim.x + threadIdx.x;
    const int e = (int)(gid >> 6);
    const int l = (int)(gid & 63);
    if (e >= E) return;
    const int d = dst[e];
    const float a = ee[e] / s[d];
    const int r = ridx ? ridx[e] : e;
    const float2 v = *(const float2*)&rows[(size_t)r * 128 + l * 2];
    atomicAdd(&c[(size_t)d * 128 + l * 2], a * v.x);
    atomicAdd(&c[(size_t)d * 128 + l * 2 + 1], a * v.y);
}

// GRU gate combine: h = relu(gru(gi, gh, h))
__global__ __launch_bounds__(256) void gru_gate_k(
    const float* __restrict__ gi, const float* __restrict__ gh,
    float* __restrict__ h, int n)
{
    const long long gid = (long long)blockIdx.x * blockDim.x + threadIdx.x;
    if (gid >= (long long)n * 128) return;
    const int i = (int)(gid >> 7);
    const int d = (int)(gid & 127);
    const size_t b = (size_t)i * 384;
    const float ir = gi[b + d], iz = gi[b + 128 + d], ig = gi[b + 256 + d];
    const float hr = gh[b + d], hz = gh[b + 128 + d], hg = gh[b + 256 + d];
    const float hv = h[gid];
    const float r  = 1.f / (1.f + expf(-(ir + hr)));
    const float z  = 1.f / (1.f + expf(-(iz + hz)));
    const float nn = tanhf(ig + r * hg);
    const float o  = (1.f - z) * nn + z * hv;
    h[gid] = fmaxf(o, 0.f);
}

__global__ __launch_bounds__(256) void readout_scatter_k(
    const float* __restrict__ x, const int* __restrict__ gidv,
    float* __restrict__ out, int* __restrict__ counts, int n)
{
    const int i = blockIdx.x * 4 + (threadIdx.x >> 6);
    const int l = threadIdx.x & 63;
    if (i >= n) return;
    const int g = gidv[i];
    const float2 v = *(const float2*)&x[(size_t)i * 128 + l * 2];
    atomicAdd(&out[(size_t)g * 128 + l * 2], v.x);
    atomicAdd(&out[(size_t)g * 128 + l * 2 + 1], v.y);
    if (l == 0) atomicAdd(&counts[g], 1);
}

__global__ __launch_bounds__(256) void readout_div_k(
    float* __restrict__ out, const int* __restrict__ counts, int G)
{
    const int gid = blockIdx.x * blockDim.x + threadIdx.x;
    if (gid >= G * 128) return;
    out[gid] /= fmaxf((float)counts[gid >> 7], 1.f);
}

// ---------------------------------------------------------------------------
extern "C" void kernel_launch(void* const* d_in, const int* in_sizes, int n_in,
                              void* d_out, int out_size, void* d_ws, size_t ws_size,
                              hipStream_t stream)
{
    const float* atom   = (const float*)d_in[0];
    const float* bond   = (const float*)d_in[1];
    const int*   src    = (const int*)d_in[2];
    const int*   dst    = (const int*)d_in[3];
    const int*   ngid   = (const int*)d_in[4];
    const float* W_node = (const float*)d_in[5];
    const float* b_node = (const float*)d_in[6];
    const float* W_e1   = (const float*)d_in[7];
    const float* b_e1   = (const float*)d_in[8];
    const float* W_e2   = (const float*)d_in[9];
    const float* b_e2   = (const float*)d_in[10];
    const float* W_et   = (const float*)d_in[11];
    const float* b_et   = (const float*)d_in[12];
    const float* g0_Wih = (const float*)d_in[13];
    const float* g0_bih = (const float*)d_in[14];
    const float* g0_Whh = (const float*)d_in[15];
    const float* g0_bhh = (const float*)d_in[16];
    const float* Wpe    = (const float*)d_in[17];
    const float* bpe    = (const float*)d_in[18];
    const float* Wpn    = (const float*)d_in[19];
    const float* bpn    = (const float*)d_in[20];
    const float* gWih   = (const float*)d_in[21];
    const float* gbih   = (const float*)d_in[22];
    const float* gWhh   = (const float*)d_in[23];
    const float* gbhh   = (const float*)d_in[24];
    const float* Wr1    = (const float*)d_in[25];
    const float* br1    = (const float*)d_in[26];
    const float* Wr2    = (const float*)d_in[27];
    const float* br2    = (const float*)d_in[28];

    const int N = in_sizes[0] / 74;
    const int E = in_sizes[1] / 12;
    const int G = out_size / 128;
    const int L = in_sizes[18];   // bpe is [L][1]

    char* w = (char*)d_ws;
    auto alloc = [&](size_t bytes) {
        void* p = (void*)w;
        w += (bytes + 255) & ~(size_t)255;
        return p;
    };
    const int Ncap = 25000;        // GRU row-chunk
    float*    h    = (float*)alloc((size_t)N * 128 * 4);
    float*    c    = (float*)alloc((size_t)N * 128 * 4);
    float*    hp   = (float*)alloc((size_t)N * 128 * 4);   // also he1/et edge chunks (<=N rows)
    float*    gruB = (float*)alloc((size_t)Ncap * 384 * 2 * 4);
    float*    pd   = (float*)alloc((size_t)N * 4);
    float*    ps   = (float*)alloc((size_t)N * 4);
    unsigned* m_u  = (unsigned*)alloc((size_t)N * 4);
    float*    sden = (float*)alloc((size_t)N * 4);
    float*    pe   = (float*)alloc((size_t)E * 4);
    float*    lg   = (float*)alloc((size_t)E * 4);
    int*      cnts = (int*)alloc((size_t)G * 4);
    if ((size_t)(w - (char*)d_ws) > ws_size) {
        fprintf(stderr, "kernel_launch: ws too small: need %zu, have %zu\n",
                (size_t)(w - (char*)d_ws), ws_size);
        return;
    }
    float* out = (float*)d_out;

    const dim3 blk(256);
    auto gemmGrid = [](int M, int NC) { return dim3((unsigned)((M + 63) / 64), (unsigned)(NC / 128)); };
    const dim3 gN128((unsigned)(((long long)N * 128 + 255) / 256));
    const dim3 gEdge((unsigned)((E + 255) / 256));
    const dim3 gWave4N((unsigned)((N + 3) / 4));
    const int  Ecap = N;           // hp holds up to N rows

    auto run_gru = [&](const float* Wih, const float* bih,
                       const float* Whh, const float* bhh) {
        float* gi = gruB;
        float* gh = gruB + (size_t)Ncap * 384;
        for (int base = 0; base < N; base += Ncap) {
            const int nc = (N - base) < Ncap ? (N - base) : Ncap;
            gemm_k<true><<<gemmGrid(nc, 384), blk, 0, stream>>>(
                c + (size_t)base * 128, nullptr, nullptr, Wih, bih, gi,
                nc, 128, 128, 384, ACT_ELU, ACT_NONE);
            gemm_k<true><<<gemmGrid(nc, 384), blk, 0, stream>>>(
                h + (size_t)base * 128, nullptr, nullptr, Whh, bhh, gh,
                nc, 128, 128, 384, ACT_NONE, ACT_NONE);
            gru_gate_k<<<dim3((unsigned)(((long long)nc * 128 + 255) / 256)), blk, 0, stream>>>(
                gi, gh, h + (size_t)base * 128, nc);
        }
    };

    // ---------------- GetContext ----------------
    gemm_k<false><<<gemmGrid(N, 128), blk, 0, stream>>>(
        atom, nullptr, nullptr, W_node, b_node, h, N, 74, 74, 128, ACT_NONE, ACT_LEAKY);
    node_dots_k<<<gWave4N, blk, 0, stream>>>(h, W_e2, nullptr, pd, nullptr, N);
    // pass A: pe[e] = he1[e] . W_e2[128:256]  (chunked, he1 in hp, discarded)
    for (int base = 0; base < E; base += Ecap) {
        const int ec = (E - base) < Ecap ? (E - base) : Ecap;
        gemm_k<false><<<gemmGrid(ec, 128), blk, 0, stream>>>(
            atom, bond + (size_t)base * 12, src + base, W_e1, b_e1, hp,
            ec, 86, 74, 128, ACT_NONE, ACT_LEAKY);
        node_dots_k<<<dim3((unsigned)((ec + 3) / 4)), blk, 0, stream>>>(
            hp, W_e2 + 128, nullptr, pe + base, nullptr, ec);
    }
    hipMemsetAsync(m_u, 0, (size_t)N * 4, stream);
    hipMemsetAsync(sden, 0, (size_t)N * 4, stream);
    edge_lgc_k<<<gEdge, blk, 0, stream>>>(pd, pe, b_e2, dst, lg, m_u, E);
    edge_exp_k<<<gEdge, blk, 0, stream>>>(lg, m_u, sden, dst, E);
    // pass B: recompute he1 chunk, apply W_et in place, scatter into c
    hipMemsetAsync(c, 0, (size_t)N * 128 * 4, stream);
    for (int base = 0; base < E; base += Ecap) {
        const int ec = (E - base) < Ecap ? (E - base) : Ecap;
        gemm_k<false><<<gemmGrid(ec, 128), blk, 0, stream>>>(
            atom, bond + (size_t)base * 12, src + base, W_e1, b_e1, hp,
            ec, 86, 74, 128, ACT_NONE, ACT_LEAKY);
        gemm_k<false><<<gemmGrid(ec, 128), blk, 0, stream>>>(
            hp, nullptr, nullptr, W_et, b_et, hp, ec, 128, 128, 128, ACT_NONE, ACT_NONE);
        scatter_c_k<<<dim3((unsigned)(((long long)ec * 64 + 255) / 256)), blk, 0, stream>>>(
            hp, nullptr, lg + base, sden, dst + base, c, ec);
    }
    run_gru(g0_Wih, g0_bih, g0_Whh, g0_bhh);

    // ---------------- 11 GNN layers ----------------
    for (int l = 0; l < L; ++l) {
        node_dots_k<<<gWave4N, blk, 0, stream>>>(
            h, Wpe + (size_t)l * 256, Wpe + (size_t)l * 256 + 128, pd, ps, N);
        hipMemsetAsync(m_u, 0, (size_t)N * 4, stream);
        hipMemsetAsync(sden, 0, (size_t)N * 4, stream);
        edge_lg_k<<<gEdge, blk, 0, stream>>>(pd, ps, bpe + l, src, dst, lg, m_u, E);
        edge_exp_k<<<gEdge, blk, 0, stream>>>(lg, m_u, sden, dst, E);
        gemm_k<false><<<gemmGrid(N, 128), blk, 0, stream>>>(
            h, nullptr, nullptr, Wpn + (size_t)l * 16384, bpn + (size_t)l * 128,
            hp, N, 128, 128, 128, ACT_NONE, ACT_NONE);
        hipMemsetAsync(c, 0, (size_t)N * 128 * 4, stream);
        scatter_c_k<<<dim3((unsigned)(((long long)E * 64 + 255) / 256)), blk, 0, stream>>>(
            hp, src, lg, sden, dst, c, E);
        run_gru(gWih + (size_t)l * 49152, gbih + (size_t)l * 384,
                gWhh + (size_t)l * 49152, gbhh + (size_t)l * 384);
    }

    // ---------------- readout ----------------
    gemm_k<false><<<gemmGrid(N, 128), blk, 0, stream>>>(
        h, nullptr, nullptr, Wr1, br1, c, N, 128, 128, 128, ACT_NONE, ACT_RELU);
    gemm_k<false><<<gemmGrid(N, 128), blk, 0, stream>>>(
        c, nullptr, nullptr, Wr2, br2, hp, N, 128, 128, 128, ACT_NONE, ACT_NONE);
    hipMemsetAsync(out, 0, (size_t)G * 128 * 4, stream);
    hipMemsetAsync(cnts, 0, (size_t)G * 4, stream);
    readout_scatter_k<<<gWave4N, blk, 0, stream>>>(hp, ngid, out, cnts, N);
    readout_div_k<<<dim3((unsigned)((G * 128 + 255) / 256)), blk, 0, stream>>>(out, cnts, G);

    (void)n_in;
}

// Round 3
// 14976.270 us; speedup vs baseline: 1.0291x; 1.0291x over previous
//
#include <hip/hip_runtime.h>
#include <cstdio>
#include <cstddef>

enum { ACT_NONE = 0, ACT_LEAKY = 1, ACT_RELU = 2, ACT_ELU = 3 };

__device__ __forceinline__ float leakyf(float x) { return x > 0.f ? x : 0.01f * x; }

// order-preserving float -> uint encoding for atomicMax
__device__ __forceinline__ unsigned fenc(float f) {
    unsigned u = __float_as_uint(f);
    return (u & 0x80000000u) ? ~u : (u | 0x80000000u);
}
__device__ __forceinline__ float fdec(unsigned u) {
    return (u & 0x80000000u) ? __uint_as_float(u & 0x7FFFFFFFu) : __uint_as_float(~u);
}

// ---------------------------------------------------------------------------
// Tiled fp32 GEMM:  C[r][colBase+c] = actOut( A'[r][:] @ B + bias )
//   A' row r = concat( A[idx? idx[r] : r][0:K1], A2[r][0:K-K1] ), actIn applied.
//   B layout: BT ? [NCtot][K] row-major (weight.T usage) : [K][NCtot] row-major.
// Block: 256 threads, tile 128 rows x 128 cols, micro-tile 8x8, KT=16.
// In-place (C == A) is safe when NCtot == 128 (one block per row range,
// epilogue-only writes).
// ---------------------------------------------------------------------------
template <bool BT>
__global__ __launch_bounds__(256, 2) void gemm_k(
    const float* __restrict__ A, const float* __restrict__ A2,
    const int* __restrict__ idx,
    const float* __restrict__ B, const float* __restrict__ bias,
    float* __restrict__ C,
    int M, int K, int K1, int NCtot, int actIn, int actOut)
{
    __shared__ float Xs[16][128];
    __shared__ float Ws[16][128];
    const int t  = threadIdx.x;
    const int tx = t & 15;   // col group: cols tx*8..+7
    const int ty = t >> 4;   // row group: rows ty*8..+7
    const int rowBase = blockIdx.x * 128;
    const int colBase = blockIdx.y * 128;

    float acc[8][8];
#pragma unroll
    for (int i = 0; i < 8; i++)
#pragma unroll
        for (int j = 0; j < 8; j++) acc[i][j] = 0.f;

    const int rS = t >> 1;          // staging row 0..127
    const int kS = (t & 1) << 3;    // staging k offset 0 or 8
    const int K2 = K - K1;

    for (int k0 = 0; k0 < K; k0 += 16) {
        // ---- stage A tile, transposed to Xs[k][row] ----
        {
            float v[8] = {0.f,0.f,0.f,0.f,0.f,0.f,0.f,0.f};
            const int row = rowBase + rS;
            if (row < M) {
                const int arow = idx ? idx[row] : row;
                const float* __restrict__ a1 = A + (size_t)arow * K1;
#pragma unroll
                for (int j = 0; j < 8; j++) {
                    const int k = k0 + kS + j;
                    float x = 0.f;
                    if (k < K1)     x = a1[k];
                    else if (k < K) x = A2[(size_t)row * K2 + (k - K1)];
                    v[j] = x;
                }
                if (actIn == ACT_ELU) {
#pragma unroll
                    for (int j = 0; j < 8; j++) v[j] = v[j] > 0.f ? v[j] : expm1f(v[j]);
                }
            }
#pragma unroll
            for (int j = 0; j < 8; j++) Xs[kS + j][rS] = v[j];
        }
        // ---- stage B tile to Ws[k][col] ----
        if (!BT) {
#pragma unroll
            for (int p = 0; p < 2; p++) {
                const int kk = (t >> 5) + p * 8;
                const int cc = (t & 31) << 2;
                const int k  = k0 + kk;
                float4 wv = make_float4(0.f, 0.f, 0.f, 0.f);
                if (k < K) wv = *(const float4*)&B[(size_t)k * NCtot + colBase + cc];
                *(float4*)&Ws[kk][cc] = wv;
            }
        } else {
            const int cc   = t >> 1;
            const int koff = (t & 1) << 3;
            const float* __restrict__ bp = B + (size_t)(colBase + cc) * K + k0 + koff;
#pragma unroll
            for (int j = 0; j < 8; j++) {
                const int k = k0 + koff + j;
                Ws[koff + j][cc] = (k < K) ? bp[j] : 0.f;
            }
        }
        __syncthreads();
#pragma unroll
        for (int k = 0; k < 16; k++) {
            const float4 xa = *(const float4*)&Xs[k][ty << 3];
            const float4 xb = *(const float4*)&Xs[k][(ty << 3) + 4];
            const float4 wa = *(const float4*)&Ws[k][tx << 3];
            const float4 wb = *(const float4*)&Ws[k][(tx << 3) + 4];
            const float xs[8]  = {xa.x, xa.y, xa.z, xa.w, xb.x, xb.y, xb.z, xb.w};
            const float ws8[8] = {wa.x, wa.y, wa.z, wa.w, wb.x, wb.y, wb.z, wb.w};
#pragma unroll
            for (int i = 0; i < 8; i++)
#pragma unroll
                for (int j = 0; j < 8; j++)
                    acc[i][j] = fmaf(xs[i], ws8[j], acc[i][j]);
        }
        __syncthreads();
    }

#pragma unroll
    for (int i = 0; i < 8; i++) {
        const int row = rowBase + (ty << 3) + i;
        if (row >= M) continue;
        float o[8];
#pragma unroll
        for (int j = 0; j < 8; j++) {
            float v = acc[i][j] + bias[colBase + (tx << 3) + j];
            if (actOut == ACT_LEAKY)      v = v > 0.f ? v : 0.01f * v;
            else if (actOut == ACT_RELU)  v = fmaxf(v, 0.f);
            o[j] = v;
        }
        float* __restrict__ cp = C + (size_t)row * NCtot + colBase + (tx << 3);
        *(float4*)cp       = make_float4(o[0], o[1], o[2], o[3]);
        *(float4*)(cp + 4) = make_float4(o[4], o[5], o[6], o[7]);
    }
}

// ---------------------------------------------------------------------------
// per-node dual dot: pd[i] = h[i]·wa, ps[i] = h[i]·wb   (one wave per node)
// ---------------------------------------------------------------------------
__global__ __launch_bounds__(256) void node_dots_k(
    const float* __restrict__ h, const float* __restrict__ wa,
    const float* __restrict__ wb, float* __restrict__ pd, float* __restrict__ ps, int n)
{
    const int i = blockIdx.x * 4 + (threadIdx.x >> 6);
    const int l = threadIdx.x & 63;
    if (i >= n) return;
    const float2 hv = *(const float2*)&h[(size_t)i * 128 + l * 2];
    float a = hv.x * wa[l * 2] + hv.y * wa[l * 2 + 1];
    float b = 0.f;
    if (wb) b = hv.x * wb[l * 2] + hv.y * wb[l * 2 + 1];
#pragma unroll
    for (int o = 32; o; o >>= 1) {
        a += __shfl_down(a, o, 64);
        b += __shfl_down(b, o, 64);
    }
    if (l == 0) {
        pd[i] = a;
        if (ps) ps[i] = b;
    }
}

// GetContext edge logits from precomputed pe: lg = leaky(pd[dst]+pe[e]+b2); atomicMax m
__global__ __launch_bounds__(256) void edge_lgc_k(
    const float* __restrict__ pd, const float* __restrict__ pe,
    const float* __restrict__ b2, const int* __restrict__ dst,
    float* __restrict__ lg, unsigned* __restrict__ m_u, int E)
{
    const int e = blockIdx.x * blockDim.x + threadIdx.x;
    if (e >= E) return;
    const int d = dst[e];
    const float v = leakyf(pd[d] + pe[e] + b2[0]);
    lg[e] = v;
    atomicMax(&m_u[d], fenc(v));
}

// e = exp(lg - m[dst]); s[dst] += e
__global__ __launch_bounds__(256) void edge_exp_k(
    float* __restrict__ lg, const unsigned* __restrict__ m_u,
    float* __restrict__ s, const int* __restrict__ dst, int E)
{
    const int e = blockIdx.x * blockDim.x + threadIdx.x;
    if (e >= E) return;
    const int d = dst[e];
    const float ex = expf(lg[e] - fdec(m_u[d]));
    lg[e] = ex;
    atomicAdd(&s[d], ex);
}

// c[dst[e]] += (ee[e]/s[dst[e]]) * rows[e]   (64 lanes x 2 cols) -- GetContext only
__global__ __launch_bounds__(256) void scatter_c_k(
    const float* __restrict__ rows,
    const float* __restrict__ ee, const float* __restrict__ s,
    const int* __restrict__ dst, float* __restrict__ c, int E)
{
    const long long gid = (long long)blockIdx.x * blockDim.x + threadIdx.x;
    const int e = (int)(gid >> 6);
    const int l = (int)(gid & 63);
    if (e >= E) return;
    const int d = dst[e];
    const float a = ee[e] / s[d];
    const float2 v = *(const float2*)&rows[(size_t)e * 128 + l * 2];
    atomicAdd(&c[(size_t)d * 128 + l * 2], a * v.x);
    atomicAdd(&c[(size_t)d * 128 + l * 2 + 1], a * v.y);
}

// ---------------------------------------------------------------------------
// CSR build: histogram -> exclusive scan -> fill
// ---------------------------------------------------------------------------
__global__ __launch_bounds__(256) void hist_k(
    const int* __restrict__ dst, unsigned* __restrict__ cnt, int E)
{
    const int e = blockIdx.x * blockDim.x + threadIdx.x;
    if (e < E) atomicAdd(&cnt[dst[e]], 1u);
}

__global__ __launch_bounds__(1024) void scan_k(
    const unsigned* __restrict__ cnt, int* __restrict__ rp, int N)
{
    __shared__ int wsum[16];
    __shared__ int carry;
    const int t = threadIdx.x, lane = t & 63, wid = t >> 6;
    if (t == 0) carry = 0;
    __syncthreads();
    for (int base = 0; base < N; base += 1024) {
        const int i = base + t;
        const int v = (i < N) ? (int)cnt[i] : 0;
        int x = v;
#pragma unroll
        for (int o = 1; o < 64; o <<= 1) {
            const int y = __shfl_up(x, o, 64);
            if (lane >= o) x += y;
        }
        if (lane == 63) wsum[wid] = x;
        __syncthreads();
        if (wid == 0) {
            const int wv = (lane < 16) ? wsum[lane] : 0;
            int wx = wv;
#pragma unroll
            for (int o = 1; o < 16; o <<= 1) {
                const int y = __shfl_up(wx, o, 64);
                if (lane >= o) wx += y;
            }
            if (lane < 16) wsum[lane] = wx - wv;   // exclusive wave offsets
        }
        __syncthreads();
        const int excl = carry + wsum[wid] + x - v;
        if (i < N) rp[i] = excl;
        __syncthreads();
        if (t == 1023) carry = excl + v;
        __syncthreads();
    }
    if (t == 0) rp[N] = carry;
}

__global__ __launch_bounds__(256) void fill_csr_k(
    const int* __restrict__ dst, int* __restrict__ pos,
    int* __restrict__ eidx, int E)
{
    const int e = blockIdx.x * blockDim.x + threadIdx.x;
    if (e < E) {
        const int p = atomicAdd(&pos[dst[e]], 1);
        eidx[p] = e;
    }
}

// ---------------------------------------------------------------------------
// Fused per-node edge softmax + weighted gather (layers):
//   c[d] = sum_e softmax_e( leaky(pd[d]+ps[src[e]]+b) ) * hp[src[e]]
// one wave per node, no atomics, coalesced c write.
// ---------------------------------------------------------------------------
__global__ __launch_bounds__(256) void layer_gather_k(
    const int* __restrict__ rp, const int* __restrict__ eidx,
    const int* __restrict__ src,
    const float* __restrict__ pd, const float* __restrict__ ps,
    const float* __restrict__ bpe,
    const float* __restrict__ hp, float* __restrict__ c, int N)
{
    const int d = blockIdx.x * 4 + (threadIdx.x >> 6);
    const int l = threadIdx.x & 63;
    if (d >= N) return;
    const int beg = rp[d], end = rp[d + 1];
    float acc0 = 0.f, acc1 = 0.f;
    if (beg < end) {
        const float pdd = pd[d];
        const float b   = bpe[0];
        float m = -3.4e38f;
        for (int e = beg + l; e < end; e += 64)
            m = fmaxf(m, leakyf(pdd + ps[src[eidx[e]]] + b));
#pragma unroll
        for (int o = 32; o; o >>= 1) m = fmaxf(m, __shfl_xor(m, o, 64));
        float s = 0.f;
        for (int e = beg + l; e < end; e += 64)
            s += expf(leakyf(pdd + ps[src[eidx[e]]] + b) - m);
#pragma unroll
        for (int o = 32; o; o >>= 1) s += __shfl_xor(s, o, 64);
        const float inv = 1.f / s;
        for (int e = beg; e < end; ++e) {
            const int sr = src[eidx[e]];                 // uniform -> broadcast
            const float a = expf(leakyf(pdd + ps[sr] + b) - m) * inv;
            const float2 v = *(const float2*)&hp[(size_t)sr * 128 + l * 2];
            acc0 = fmaf(a, v.x, acc0);
            acc1 = fmaf(a, v.y, acc1);
        }
    }
    *(float2*)&c[(size_t)d * 128 + l * 2] = make_float2(acc0, acc1);
}

// GRU gate combine: h = relu(gru(gi, gh, h))
__global__ __launch_bounds__(256) void gru_gate_k(
    const float* __restrict__ gi, const float* __restrict__ gh,
    float* __restrict__ h, int n)
{
    const long long gid = (long long)blockIdx.x * blockDim.x + threadIdx.x;
    if (gid >= (long long)n * 128) return;
    const int i = (int)(gid >> 7);
    const int d = (int)(gid & 127);
    const size_t b = (size_t)i * 384;
    const float ir = gi[b + d], iz = gi[b + 128 + d], ig = gi[b + 256 + d];
    const float hr = gh[b + d], hz = gh[b + 128 + d], hg = gh[b + 256 + d];
    const float hv = h[gid];
    const float r  = 1.f / (1.f + expf(-(ir + hr)));
    const float z  = 1.f / (1.f + expf(-(iz + hz)));
    const float nn = tanhf(ig + r * hg);
    const float o  = (1.f - z) * nn + z * hv;
    h[gid] = fmaxf(o, 0.f);
}

__global__ __launch_bounds__(256) void readout_scatter_k(
    const float* __restrict__ x, const int* __restrict__ gidv,
    float* __restrict__ out, int* __restrict__ counts, int n)
{
    const int i = blockIdx.x * 4 + (threadIdx.x >> 6);
    const int l = threadIdx.x & 63;
    if (i >= n) return;
    const int g = gidv[i];
    const float2 v = *(const float2*)&x[(size_t)i * 128 + l * 2];
    atomicAdd(&out[(size_t)g * 128 + l * 2], v.x);
    atomicAdd(&out[(size_t)g * 128 + l * 2 + 1], v.y);
    if (l == 0) atomicAdd(&counts[g], 1);
}

__global__ __launch_bounds__(256) void readout_div_k(
    float* __restrict__ out, const int* __restrict__ counts, int G)
{
    const int gid = blockIdx.x * blockDim.x + threadIdx.x;
    if (gid >= G * 128) return;
    out[gid] /= fmaxf((float)counts[gid >> 7], 1.f);
}

// ---------------------------------------------------------------------------
extern "C" void kernel_launch(void* const* d_in, const int* in_sizes, int n_in,
                              void* d_out, int out_size, void* d_ws, size_t ws_size,
                              hipStream_t stream)
{
    const float* atom   = (const float*)d_in[0];
    const float* bond   = (const float*)d_in[1];
    const int*   src    = (const int*)d_in[2];
    const int*   dst    = (const int*)d_in[3];
    const int*   ngid   = (const int*)d_in[4];
    const float* W_node = (const float*)d_in[5];
    const float* b_node = (const float*)d_in[6];
    const float* W_e1   = (const float*)d_in[7];
    const float* b_e1   = (const float*)d_in[8];
    const float* W_e2   = (const float*)d_in[9];
    const float* b_e2   = (const float*)d_in[10];
    const float* W_et   = (const float*)d_in[11];
    const float* b_et   = (const float*)d_in[12];
    const float* g0_Wih = (const float*)d_in[13];
    const float* g0_bih = (const float*)d_in[14];
    const float* g0_Whh = (const float*)d_in[15];
    const float* g0_bhh = (const float*)d_in[16];
    const float* Wpe    = (const float*)d_in[17];
    const float* bpe    = (const float*)d_in[18];
    const float* Wpn    = (const float*)d_in[19];
    const float* bpn    = (const float*)d_in[20];
    const float* gWih   = (const float*)d_in[21];
    const float* gbih   = (const float*)d_in[22];
    const float* gWhh   = (const float*)d_in[23];
    const float* gbhh   = (const float*)d_in[24];
    const float* Wr1    = (const float*)d_in[25];
    const float* br1    = (const float*)d_in[26];
    const float* Wr2    = (const float*)d_in[27];
    const float* br2    = (const float*)d_in[28];

    const int N = in_sizes[0] / 74;
    const int E = in_sizes[1] / 12;
    const int G = out_size / 128;
    const int L = in_sizes[18];   // bpe is [L][1]

    char* w = (char*)d_ws;
    auto alloc = [&](size_t bytes) {
        void* p = (void*)w;
        w += (bytes + 255) & ~(size_t)255;
        return p;
    };
    const int Ncap = 25000;        // GRU row-chunk
    float*    h    = (float*)alloc((size_t)N * 128 * 4);
    float*    c    = (float*)alloc((size_t)N * 128 * 4);
    float*    hp   = (float*)alloc((size_t)N * 128 * 4);   // also he1 edge chunks (<=N rows)
    float*    gruB = (float*)alloc((size_t)Ncap * 384 * 2 * 4);
    float*    pd   = (float*)alloc((size_t)N * 4);
    float*    ps   = (float*)alloc((size_t)N * 4);
    unsigned* m_u  = (unsigned*)alloc((size_t)N * 4);      // also CSR histogram
    float*    sden = (float*)alloc((size_t)N * 4);
    float*    pe   = (float*)alloc((size_t)E * 4);
    float*    lg   = (float*)alloc((size_t)E * 4);
    int*      rp   = (int*)alloc((size_t)(N + 1) * 4);
    int*      posb = (int*)alloc((size_t)N * 4);
    int*      eidx = (int*)alloc((size_t)E * 4);
    int*      cnts = (int*)alloc((size_t)G * 4);
    if ((size_t)(w - (char*)d_ws) > ws_size) {
        fprintf(stderr, "kernel_launch: ws too small: need %zu, have %zu\n",
                (size_t)(w - (char*)d_ws), ws_size);
        return;
    }
    float* out = (float*)d_out;

    const dim3 blk(256);
    auto gemmGrid = [](int M, int NC) { return dim3((unsigned)((M + 127) / 128), (unsigned)(NC / 128)); };
    const dim3 gEdge((unsigned)((E + 255) / 256));
    const dim3 gWave4N((unsigned)((N + 3) / 4));
    const int  Ecap = N;           // hp holds up to N rows

    auto run_gru = [&](const float* Wih, const float* bih,
                       const float* Whh, const float* bhh) {
        float* gi = gruB;
        float* gh = gruB + (size_t)Ncap * 384;
        for (int base = 0; base < N; base += Ncap) {
            const int nc = (N - base) < Ncap ? (N - base) : Ncap;
            gemm_k<true><<<gemmGrid(nc, 384), blk, 0, stream>>>(
                c + (size_t)base * 128, nullptr, nullptr, Wih, bih, gi,
                nc, 128, 128, 384, ACT_ELU, ACT_NONE);
            gemm_k<true><<<gemmGrid(nc, 384), blk, 0, stream>>>(
                h + (size_t)base * 128, nullptr, nullptr, Whh, bhh, gh,
                nc, 128, 128, 384, ACT_NONE, ACT_NONE);
            gru_gate_k<<<dim3((unsigned)(((long long)nc * 128 + 255) / 256)), blk, 0, stream>>>(
                gi, gh, h + (size_t)base * 128, nc);
        }
    };

    // ---------------- CSR build (graph static across layers) ----------------
    hipMemsetAsync(m_u, 0, (size_t)N * 4, stream);
    hist_k<<<gEdge, blk, 0, stream>>>(dst, m_u, E);
    scan_k<<<dim3(1), dim3(1024), 0, stream>>>(m_u, rp, N);
    hipMemcpyAsync(posb, rp, (size_t)N * 4, hipMemcpyDeviceToDevice, stream);
    fill_csr_k<<<gEdge, blk, 0, stream>>>(dst, posb, eidx, E);

    // ---------------- GetContext ----------------
    gemm_k<false><<<gemmGrid(N, 128), blk, 0, stream>>>(
        atom, nullptr, nullptr, W_node, b_node, h, N, 74, 74, 128, ACT_NONE, ACT_LEAKY);
    node_dots_k<<<gWave4N, blk, 0, stream>>>(h, W_e2, nullptr, pd, nullptr, N);
    // pass A: pe[e] = he1[e] . W_e2[128:256]  (chunked, he1 in hp, discarded)
    for (int base = 0; base < E; base += Ecap) {
        const int ec = (E - base) < Ecap ? (E - base) : Ecap;
        gemm_k<false><<<gemmGrid(ec, 128), blk, 0, stream>>>(
            atom, bond + (size_t)base * 12, src + base, W_e1, b_e1, hp,
            ec, 86, 74, 128, ACT_NONE, ACT_LEAKY);
        node_dots_k<<<dim3((unsigned)((ec + 3) / 4)), blk, 0, stream>>>(
            hp, W_e2 + 128, nullptr, pe + base, nullptr, ec);
    }
    hipMemsetAsync(m_u, 0, (size_t)N * 4, stream);
    hipMemsetAsync(sden, 0, (size_t)N * 4, stream);
    edge_lgc_k<<<gEdge, blk, 0, stream>>>(pd, pe, b_e2, dst, lg, m_u, E);
    edge_exp_k<<<gEdge, blk, 0, stream>>>(lg, m_u, sden, dst, E);
    // pass B: recompute he1 chunk, scatter a*he1 into c; then c = c@W_et + b_et
    // (valid because sum_e a_e = 1 per node: softmax weights)
    hipMemsetAsync(c, 0, (size_t)N * 128 * 4, stream);
    for (int base = 0; base < E; base += Ecap) {
        const int ec = (E - base) < Ecap ? (E - base) : Ecap;
        gemm_k<false><<<gemmGrid(ec, 128), blk, 0, stream>>>(
            atom, bond + (size_t)base * 12, src + base, W_e1, b_e1, hp,
            ec, 86, 74, 128, ACT_NONE, ACT_LEAKY);
        scatter_c_k<<<dim3((unsigned)(((long long)ec * 64 + 255) / 256)), blk, 0, stream>>>(
            hp, lg + base, sden, dst + base, c, ec);
    }
    gemm_k<false><<<gemmGrid(N, 128), blk, 0, stream>>>(
        c, nullptr, nullptr, W_et, b_et, c, N, 128, 128, 128, ACT_NONE, ACT_NONE);
    run_gru(g0_Wih, g0_bih, g0_Whh, g0_bhh);

    // ---------------- 11 GNN layers ----------------
    for (int l = 0; l < L; ++l) {
        node_dots_k<<<gWave4N, blk, 0, stream>>>(
            h, Wpe + (size_t)l * 256, Wpe + (size_t)l * 256 + 128, pd, ps, N);
        gemm_k<false><<<gemmGrid(N, 128), blk, 0, stream>>>(
            h, nullptr, nullptr, Wpn + (size_t)l * 16384, bpn + (size_t)l * 128,
            hp, N, 128, 128, 128, ACT_NONE, ACT_NONE);
        layer_gather_k<<<gWave4N, blk, 0, stream>>>(
            rp, eidx, src, pd, ps, bpe + l, hp, c, N);
        run_gru(gWih + (size_t)l * 49152, gbih + (size_t)l * 384,
                gWhh + (size_t)l * 49152, gbhh + (size_t)l * 384);
    }

    // ---------------- readout ----------------
    gemm_k<false><<<gemmGrid(N, 128), blk, 0, stream>>>(
        h, nullptr, nullptr, Wr1, br1, c, N, 128, 128, 128, ACT_NONE, ACT_RELU);
    gemm_k<false><<<gemmGrid(N, 128), blk, 0, stream>>>(
        c, nullptr, nullptr, Wr2, br2, hp, N, 128, 128, 128, ACT_NONE, ACT_NONE);
    hipMemsetAsync(out, 0, (size_t)G * 128 * 4, stream);
    hipMemsetAsync(cnts, 0, (size_t)G * 4, stream);
    readout_scatter_k<<<gWave4N, blk, 0, stream>>>(hp, ngid, out, cnts, N);
    readout_div_k<<<dim3((unsigned)((G * 128 + 255) / 256)), blk, 0, stream>>>(out, cnts, G);

    (void)n_in;
}

// Round 4
// 7400.482 us; speedup vs baseline: 2.0826x; 2.0237x over previous
//
#include <hip/hip_runtime.h>
#include <cstdio>
#include <cstddef>

enum { ACT_NONE = 0, ACT_LEAKY = 1, ACT_RELU = 2 };

__device__ __forceinline__ float leakyf(float x) { return x > 0.f ? x : 0.01f * x; }

// order-preserving float -> uint encoding for atomicMax
__device__ __forceinline__ unsigned fenc(float f) {
    unsigned u = __float_as_uint(f);
    return (u & 0x80000000u) ? ~u : (u | 0x80000000u);
}
__device__ __forceinline__ float fdec(unsigned u) {
    return (u & 0x80000000u) ? __uint_as_float(u & 0x7FFFFFFFu) : __uint_as_float(~u);
}

// ---------------------------------------------------------------------------
// fp32 GEMM, NC = 128 fixed:  C[r][c] = actOut( A'[r][:] @ B + bias )
//   A' row r = concat( A[idx? idx[r] : r][0:K1], A2[r][0:K-K1] ).
//   B: [K][128] row-major.
// 256 threads, tile 64 rows x 128 cols, micro 4 rows x (4+4) cols {c, c+64}.
// In-place (C == A) safe: block reads only its own 64 rows, writes in epilogue.
// ---------------------------------------------------------------------------
__global__ __launch_bounds__(256, 2) void gemm_k(
    const float* __restrict__ A, const float* __restrict__ A2,
    const int* __restrict__ idx,
    const float* __restrict__ B, const float* __restrict__ bias,
    float* __restrict__ C, int M, int K, int K1, int actOut)
{
    __shared__ float Xs[16][64];
    __shared__ float Ws[16][128];
    const int t  = threadIdx.x;
    const int cg = t & 15;        // cols cg*4..+3 and 64+cg*4..+3
    const int rg = t >> 4;        // rows rg*4..+3
    const int rowBase = blockIdx.x * 64;

    float acc[4][8];
#pragma unroll
    for (int i = 0; i < 4; i++)
#pragma unroll
        for (int j = 0; j < 8; j++) acc[i][j] = 0.f;

    const int rS = t >> 2;        // 0..63
    const int kS = (t & 3) << 2;  // 0/4/8/12
    const int K2 = K - K1;

    for (int k0 = 0; k0 < K; k0 += 16) {
        // ---- stage A tile (transposed) ----
        {
            float v[4] = {0.f, 0.f, 0.f, 0.f};
            const int row = rowBase + rS;
            if (row < M) {
                const int ar = idx ? idx[row] : row;
                const float* __restrict__ a1 = A + (size_t)ar * K1;
#pragma unroll
                for (int j = 0; j < 4; j++) {
                    const int k = k0 + kS + j;
                    float x = 0.f;
                    if (k < K1)     x = a1[k];
                    else if (k < K) x = A2[(size_t)row * K2 + (k - K1)];
                    v[j] = x;
                }
            }
#pragma unroll
            for (int j = 0; j < 4; j++) Xs[kS + j][rS] = v[j];
        }
        // ---- stage B tile ----
        {
            const int cc = (t & 31) << 2;
#pragma unroll
            for (int p = 0; p < 2; p++) {
                const int kk = (t >> 5) + p * 8;
                const int k  = k0 + kk;
                float4 wv = make_float4(0.f, 0.f, 0.f, 0.f);
                if (k < K) wv = *(const float4*)&B[(size_t)k * 128 + cc];
                *(float4*)&Ws[kk][cc] = wv;
            }
        }
        __syncthreads();
#pragma unroll
        for (int k = 0; k < 16; k++) {
            const float4 xv = *(const float4*)&Xs[k][rg << 2];
            const float4 w0 = *(const float4*)&Ws[k][cg << 2];
            const float4 w1 = *(const float4*)&Ws[k][64 + (cg << 2)];
            const float xr[4] = {xv.x, xv.y, xv.z, xv.w};
            const float wc[8] = {w0.x, w0.y, w0.z, w0.w, w1.x, w1.y, w1.z, w1.w};
#pragma unroll
            for (int i = 0; i < 4; i++)
#pragma unroll
                for (int j = 0; j < 8; j++)
                    acc[i][j] = fmaf(xr[i], wc[j], acc[i][j]);
        }
        __syncthreads();
    }

    const int c0 = cg << 2;
#pragma unroll
    for (int i = 0; i < 4; i++) {
        const int row = rowBase + (rg << 2) + i;
        if (row >= M) continue;
        float o[8];
#pragma unroll
        for (int j = 0; j < 8; j++) {
            const int col = (j < 4) ? (c0 + j) : (64 + c0 + j - 4);
            float v = acc[i][j] + bias[col];
            if (actOut == ACT_LEAKY)      v = v > 0.f ? v : 0.01f * v;
            else if (actOut == ACT_RELU)  v = fmaxf(v, 0.f);
            o[j] = v;
        }
        float* __restrict__ cp = C + (size_t)row * 128;
        *(float4*)(cp + c0)      = make_float4(o[0], o[1], o[2], o[3]);
        *(float4*)(cp + 64 + c0) = make_float4(o[4], o[5], o[6], o[7]);
    }
}

// ---------------------------------------------------------------------------
// GRU GEMM (K = 128, NC = 384, W in [384][128] weight.T layout).
// 512 threads, tile 64 rows x 384 cols; micro: 4 rows x {c, c+128, c+256}x4,
// so each thread owns the full (r,z,n) gate triple for its 4 gate-dims.
//   GATE=false: gi = elu(A) @ W.T + bias      (A = c)
//   GATE=true : gh = A @ W.T + bias; h = relu(gru(gi, gh, h))  (A = h, in-place)
// ---------------------------------------------------------------------------
template <bool GATE>
__global__ __launch_bounds__(512) void gru_gemm_k(
    const float* __restrict__ A, const float* __restrict__ W,
    const float* __restrict__ bias,
    float* __restrict__ gi, float* __restrict__ h, int M)
{
    __shared__ float Xs[16][64];
    __shared__ float Ws[16][384];
    const int t  = threadIdx.x;
    const int cg = t & 31;        // gate-dims cg*4..+3
    const int rg = t >> 5;        // rows rg*4..+3 (0..15)
    const int rowBase = blockIdx.x * 64;

    float acc[3][4][4];
#pragma unroll
    for (int g = 0; g < 3; g++)
#pragma unroll
        for (int i = 0; i < 4; i++)
#pragma unroll
            for (int j = 0; j < 4; j++) acc[g][i][j] = 0.f;

    const int rS = t >> 3;        // 0..63
    const int kS = (t & 7) << 1;  // 0,2,..,14

    for (int k0 = 0; k0 < 128; k0 += 16) {
        // ---- stage A (transposed), optional ELU ----
        {
            float v0 = 0.f, v1 = 0.f;
            const int row = rowBase + rS;
            if (row < M) {
                const float2 a = *(const float2*)&A[(size_t)row * 128 + k0 + kS];
                v0 = a.x; v1 = a.y;
                if (!GATE) {
                    v0 = v0 > 0.f ? v0 : expm1f(v0);
                    v1 = v1 > 0.f ? v1 : expm1f(v1);
                }
            }
            Xs[kS][rS]     = v0;
            Xs[kS + 1][rS] = v1;
        }
        // ---- stage W: 3 coalesced float4 per thread ----
#pragma unroll
        for (int i = 0; i < 3; i++) {
            const int l   = t + 512 * i;      // 0..1535
            const int col = l >> 2;           // 0..383
            const int k4  = (l & 3) << 2;     // 0,4,8,12
            const float4 w = *(const float4*)&W[(size_t)col * 128 + k0 + k4];
            Ws[k4 + 0][col] = w.x;
            Ws[k4 + 1][col] = w.y;
            Ws[k4 + 2][col] = w.z;
            Ws[k4 + 3][col] = w.w;
        }
        __syncthreads();
#pragma unroll
        for (int k = 0; k < 16; k++) {
            const float4 xv = *(const float4*)&Xs[k][rg << 2];
            const float xr[4] = {xv.x, xv.y, xv.z, xv.w};
#pragma unroll
            for (int g = 0; g < 3; g++) {
                const float4 wv = *(const float4*)&Ws[k][g * 128 + (cg << 2)];
                const float wc[4] = {wv.x, wv.y, wv.z, wv.w};
#pragma unroll
                for (int i = 0; i < 4; i++)
#pragma unroll
                    for (int j = 0; j < 4; j++)
                        acc[g][i][j] = fmaf(xr[i], wc[j], acc[g][i][j]);
            }
        }
        __syncthreads();
    }

    const int c0 = cg << 2;
#pragma unroll
    for (int i = 0; i < 4; i++) {
        const int row = rowBase + (rg << 2) + i;
        if (row >= M) continue;
        if (!GATE) {
            float* __restrict__ gp = gi + (size_t)row * 384;
#pragma unroll
            for (int g = 0; g < 3; g++) {
                float4 o;
                o.x = acc[g][i][0] + bias[g * 128 + c0 + 0];
                o.y = acc[g][i][1] + bias[g * 128 + c0 + 1];
                o.z = acc[g][i][2] + bias[g * 128 + c0 + 2];
                o.w = acc[g][i][3] + bias[g * 128 + c0 + 3];
                *(float4*)(gp + g * 128 + c0) = o;
            }
        } else {
            const float* __restrict__ gp = gi + (size_t)row * 384;
            const float4 q0 = *(const float4*)(gp + c0);
            const float4 q1 = *(const float4*)(gp + 128 + c0);
            const float4 q2 = *(const float4*)(gp + 256 + c0);
            const float4 hq = *(const float4*)&h[(size_t)row * 128 + c0];
            const float ir[4] = {q0.x, q0.y, q0.z, q0.w};
            const float iz[4] = {q1.x, q1.y, q1.z, q1.w};
            const float ig[4] = {q2.x, q2.y, q2.z, q2.w};
            const float hv[4] = {hq.x, hq.y, hq.z, hq.w};
            float o[4];
#pragma unroll
            for (int j = 0; j < 4; j++) {
                const float hr = acc[0][i][j] + bias[c0 + j];
                const float hz = acc[1][i][j] + bias[128 + c0 + j];
                const float hg = acc[2][i][j] + bias[256 + c0 + j];
                const float r  = 1.f / (1.f + expf(-(ir[j] + hr)));
                const float z  = 1.f / (1.f + expf(-(iz[j] + hz)));
                const float nn = tanhf(ig[j] + r * hg);
                o[j] = fmaxf((1.f - z) * nn + z * hv[j], 0.f);
            }
            *(float4*)&h[(size_t)row * 128 + c0] = make_float4(o[0], o[1], o[2], o[3]);
        }
    }
}

// ---------------------------------------------------------------------------
// per-node dual dot: pd[i] = h[i]·wa, ps[i] = h[i]·wb   (one wave per node)
// ---------------------------------------------------------------------------
__global__ __launch_bounds__(256) void node_dots_k(
    const float* __restrict__ h, const float* __restrict__ wa,
    const float* __restrict__ wb, float* __restrict__ pd, float* __restrict__ ps, int n)
{
    const int i = blockIdx.x * 4 + (threadIdx.x >> 6);
    const int l = threadIdx.x & 63;
    if (i >= n) return;
    const float2 hv = *(const float2*)&h[(size_t)i * 128 + l * 2];
    float a = hv.x * wa[l * 2] + hv.y * wa[l * 2 + 1];
    float b = 0.f;
    if (wb) b = hv.x * wb[l * 2] + hv.y * wb[l * 2 + 1];
#pragma unroll
    for (int o = 32; o; o >>= 1) {
        a += __shfl_down(a, o, 64);
        b += __shfl_down(b, o, 64);
    }
    if (l == 0) {
        pd[i] = a;
        if (ps) ps[i] = b;
    }
}

// GetContext edge logits from precomputed pe: lg = leaky(pd[dst]+pe[e]+b2); atomicMax m
__global__ __launch_bounds__(256) void edge_lgc_k(
    const float* __restrict__ pd, const float* __restrict__ pe,
    const float* __restrict__ b2, const int* __restrict__ dst,
    float* __restrict__ lg, unsigned* __restrict__ m_u, int E)
{
    const int e = blockIdx.x * blockDim.x + threadIdx.x;
    if (e >= E) return;
    const int d = dst[e];
    const float v = leakyf(pd[d] + pe[e] + b2[0]);
    lg[e] = v;
    atomicMax(&m_u[d], fenc(v));
}

// e = exp(lg - m[dst]); s[dst] += e
__global__ __launch_bounds__(256) void edge_exp_k(
    float* __restrict__ lg, const unsigned* __restrict__ m_u,
    float* __restrict__ s, const int* __restrict__ dst, int E)
{
    const int e = blockIdx.x * blockDim.x + threadIdx.x;
    if (e >= E) return;
    const int d = dst[e];
    const float ex = expf(lg[e] - fdec(m_u[d]));
    lg[e] = ex;
    atomicAdd(&s[d], ex);
}

// c[dst[e]] += (ee[e]/s[dst[e]]) * rows[e]   (64 lanes x 2 cols) -- GetContext only
__global__ __launch_bounds__(256) void scatter_c_k(
    const float* __restrict__ rows,
    const float* __restrict__ ee, const float* __restrict__ s,
    const int* __restrict__ dst, float* __restrict__ c, int E)
{
    const long long gid = (long long)blockIdx.x * blockDim.x + threadIdx.x;
    const int e = (int)(gid >> 6);
    const int l = (int)(gid & 63);
    if (e >= E) return;
    const int d = dst[e];
    const float a = ee[e] / s[d];
    const float2 v = *(const float2*)&rows[(size_t)e * 128 + l * 2];
    atomicAdd(&c[(size_t)d * 128 + l * 2], a * v.x);
    atomicAdd(&c[(size_t)d * 128 + l * 2 + 1], a * v.y);
}

// ---------------------------------------------------------------------------
// CSR build: histogram -> exclusive scan -> fill
// ---------------------------------------------------------------------------
__global__ __launch_bounds__(256) void hist_k(
    const int* __restrict__ dst, unsigned* __restrict__ cnt, int E)
{
    const int e = blockIdx.x * blockDim.x + threadIdx.x;
    if (e < E) atomicAdd(&cnt[dst[e]], 1u);
}

__global__ __launch_bounds__(1024) void scan_k(
    const unsigned* __restrict__ cnt, int* __restrict__ rp, int N)
{
    __shared__ int wsum[16];
    __shared__ int carry;
    const int t = threadIdx.x, lane = t & 63, wid = t >> 6;
    if (t == 0) carry = 0;
    __syncthreads();
    for (int base = 0; base < N; base += 1024) {
        const int i = base + t;
        const int v = (i < N) ? (int)cnt[i] : 0;
        int x = v;
#pragma unroll
        for (int o = 1; o < 64; o <<= 1) {
            const int y = __shfl_up(x, o, 64);
            if (lane >= o) x += y;
        }
        if (lane == 63) wsum[wid] = x;
        __syncthreads();
        if (wid == 0) {
            const int wv = (lane < 16) ? wsum[lane] : 0;
            int wx = wv;
#pragma unroll
            for (int o = 1; o < 16; o <<= 1) {
                const int y = __shfl_up(wx, o, 64);
                if (lane >= o) wx += y;
            }
            if (lane < 16) wsum[lane] = wx - wv;   // exclusive wave offsets
        }
        __syncthreads();
        const int excl = carry + wsum[wid] + x - v;
        if (i < N) rp[i] = excl;
        __syncthreads();
        if (t == 1023) carry = excl + v;
        __syncthreads();
    }
    if (t == 0) rp[N] = carry;
}

__global__ __launch_bounds__(256) void fill_csr_k(
    const int* __restrict__ dst, int* __restrict__ pos,
    int* __restrict__ eidx, int E)
{
    const int e = blockIdx.x * blockDim.x + threadIdx.x;
    if (e < E) {
        const int p = atomicAdd(&pos[dst[e]], 1);
        eidx[p] = e;
    }
}

// ---------------------------------------------------------------------------
// Fused per-node edge softmax + weighted gather (layers):
//   c[d] = sum_e softmax_e( leaky(pd[d]+ps[src[e]]+b) ) * hp[src[e]]
// one wave per node, no atomics, coalesced c write.
// ---------------------------------------------------------------------------
__global__ __launch_bounds__(256) void layer_gather_k(
    const int* __restrict__ rp, const int* __restrict__ eidx,
    const int* __restrict__ src,
    const float* __restrict__ pd, const float* __restrict__ ps,
    const float* __restrict__ bpe,
    const float* __restrict__ hp, float* __restrict__ c, int N)
{
    const int d = blockIdx.x * 4 + (threadIdx.x >> 6);
    const int l = threadIdx.x & 63;
    if (d >= N) return;
    const int beg = rp[d], end = rp[d + 1];
    float acc0 = 0.f, acc1 = 0.f;
    if (beg < end) {
        const float pdd = pd[d];
        const float b   = bpe[0];
        float m = -3.4e38f;
        for (int e = beg + l; e < end; e += 64)
            m = fmaxf(m, leakyf(pdd + ps[src[eidx[e]]] + b));
#pragma unroll
        for (int o = 32; o; o >>= 1) m = fmaxf(m, __shfl_xor(m, o, 64));
        float s = 0.f;
        for (int e = beg + l; e < end; e += 64)
            s += expf(leakyf(pdd + ps[src[eidx[e]]] + b) - m);
#pragma unroll
        for (int o = 32; o; o >>= 1) s += __shfl_xor(s, o, 64);
        const float inv = 1.f / s;
        for (int e = beg; e < end; ++e) {
            const int sr = src[eidx[e]];                 // uniform -> broadcast
            const float a = expf(leakyf(pdd + ps[sr] + b) - m) * inv;
            const float2 v = *(const float2*)&hp[(size_t)sr * 128 + l * 2];
            acc0 = fmaf(a, v.x, acc0);
            acc1 = fmaf(a, v.y, acc1);
        }
    }
    *(float2*)&c[(size_t)d * 128 + l * 2] = make_float2(acc0, acc1);
}

__global__ __launch_bounds__(256) void readout_scatter_k(
    const float* __restrict__ x, const int* __restrict__ gidv,
    float* __restrict__ out, int* __restrict__ counts, int n)
{
    const int i = blockIdx.x * 4 + (threadIdx.x >> 6);
    const int l = threadIdx.x & 63;
    if (i >= n) return;
    const int g = gidv[i];
    const float2 v = *(const float2*)&x[(size_t)i * 128 + l * 2];
    atomicAdd(&out[(size_t)g * 128 + l * 2], v.x);
    atomicAdd(&out[(size_t)g * 128 + l * 2 + 1], v.y);
    if (l == 0) atomicAdd(&counts[g], 1);
}

__global__ __launch_bounds__(256) void readout_div_k(
    float* __restrict__ out, const int* __restrict__ counts, int G)
{
    const int gid = blockIdx.x * blockDim.x + threadIdx.x;
    if (gid >= G * 128) return;
    out[gid] /= fmaxf((float)counts[gid >> 7], 1.f);
}

// ---------------------------------------------------------------------------
extern "C" void kernel_launch(void* const* d_in, const int* in_sizes, int n_in,
                              void* d_out, int out_size, void* d_ws, size_t ws_size,
                              hipStream_t stream)
{
    const float* atom   = (const float*)d_in[0];
    const float* bond   = (const float*)d_in[1];
    const int*   src    = (const int*)d_in[2];
    const int*   dst    = (const int*)d_in[3];
    const int*   ngid   = (const int*)d_in[4];
    const float* W_node = (const float*)d_in[5];
    const float* b_node = (const float*)d_in[6];
    const float* W_e1   = (const float*)d_in[7];
    const float* b_e1   = (const float*)d_in[8];
    const float* W_e2   = (const float*)d_in[9];
    const float* b_e2   = (const float*)d_in[10];
    const float* W_et   = (const float*)d_in[11];
    const float* b_et   = (const float*)d_in[12];
    const float* g0_Wih = (const float*)d_in[13];
    const float* g0_bih = (const float*)d_in[14];
    const float* g0_Whh = (const float*)d_in[15];
    const float* g0_bhh = (const float*)d_in[16];
    const float* Wpe    = (const float*)d_in[17];
    const float* bpe    = (const float*)d_in[18];
    const float* Wpn    = (const float*)d_in[19];
    const float* bpn    = (const float*)d_in[20];
    const float* gWih   = (const float*)d_in[21];
    const float* gbih   = (const float*)d_in[22];
    const float* gWhh   = (const float*)d_in[23];
    const float* gbhh   = (const float*)d_in[24];
    const float* Wr1    = (const float*)d_in[25];
    const float* br1    = (const float*)d_in[26];
    const float* Wr2    = (const float*)d_in[27];
    const float* br2    = (const float*)d_in[28];

    const int N = in_sizes[0] / 74;
    const int E = in_sizes[1] / 12;
    const int G = out_size / 128;
    const int L = in_sizes[18];   // bpe is [L][1]

    char* w = (char*)d_ws;
    auto align256 = [](size_t b) { return (b + 255) & ~(size_t)255; };
    auto alloc = [&](size_t bytes) {
        void* p = (void*)w;
        w += align256(bytes);
        return p;
    };
    // region 1: live across everything
    float* h    = (float*)alloc((size_t)N * 128 * 4);
    float* c    = (float*)alloc((size_t)N * 128 * 4);
    int*   rp   = (int*)alloc((size_t)(N + 1) * 4);
    int*   posb = (int*)alloc((size_t)N * 4);
    int*   eidx = (int*)alloc((size_t)E * 4);
    int*   cnts = (int*)alloc((size_t)G * 4);
    // union region: gi (N*384) overlays {hp, pd, ps, m_u, sden, pe, lg}
    char* ubase = w;
    float* gi = (float*)ubase;
    char* u = ubase;
    auto ualloc = [&](size_t bytes) {
        void* p = (void*)u;
        u += align256(bytes);
        return p;
    };
    float*    hp   = (float*)ualloc((size_t)N * 128 * 4);
    float*    pd   = (float*)ualloc((size_t)N * 4);
    float*    ps   = (float*)ualloc((size_t)N * 4);
    unsigned* m_u  = (unsigned*)ualloc((size_t)N * 4);
    float*    sden = (float*)ualloc((size_t)N * 4);
    float*    pe   = (float*)ualloc((size_t)E * 4);
    float*    lg   = (float*)ualloc((size_t)E * 4);
    const size_t usize = (size_t)(u - ubase) > (size_t)N * 384 * 4
                             ? (size_t)(u - ubase) : (size_t)N * 384 * 4;
    const size_t need = (size_t)(ubase - (char*)d_ws) + align256(usize);
    if (need > ws_size) {
        fprintf(stderr, "kernel_launch: ws too small: need %zu, have %zu\n",
                need, ws_size);
        return;
    }
    float* out = (float*)d_out;

    const dim3 blk(256);
    const dim3 blk512(512);
    auto g64 = [](int M) { return dim3((unsigned)((M + 63) / 64)); };
    const dim3 gEdge((unsigned)((E + 255) / 256));
    const dim3 gWave4N((unsigned)((N + 3) / 4));
    const int  Ecap = N;           // hp holds up to N rows

    auto run_gru = [&](const float* Wih, const float* bih,
                       const float* Whh, const float* bhh) {
        gru_gemm_k<false><<<g64(N), blk512, 0, stream>>>(c, Wih, bih, gi, nullptr, N);
        gru_gemm_k<true><<<g64(N), blk512, 0, stream>>>(h, Whh, bhh, gi, h, N);
    };

    // ---------------- CSR build (graph static across layers) ----------------
    hipMemsetAsync(m_u, 0, (size_t)N * 4, stream);
    hist_k<<<gEdge, blk, 0, stream>>>(dst, m_u, E);
    scan_k<<<dim3(1), dim3(1024), 0, stream>>>(m_u, rp, N);
    hipMemcpyAsync(posb, rp, (size_t)N * 4, hipMemcpyDeviceToDevice, stream);
    fill_csr_k<<<gEdge, blk, 0, stream>>>(dst, posb, eidx, E);

    // ---------------- GetContext ----------------
    gemm_k<<<g64(N), blk, 0, stream>>>(
        atom, nullptr, nullptr, W_node, b_node, h, N, 74, 74, ACT_LEAKY);
    node_dots_k<<<gWave4N, blk, 0, stream>>>(h, W_e2, nullptr, pd, nullptr, N);
    // pass A: pe[e] = he1[e] . W_e2[128:256]  (chunked, he1 in hp, discarded)
    for (int base = 0; base < E; base += Ecap) {
        const int ec = (E - base) < Ecap ? (E - base) : Ecap;
        gemm_k<<<g64(ec), blk, 0, stream>>>(
            atom, bond + (size_t)base * 12, src + base, W_e1, b_e1, hp,
            ec, 86, 74, ACT_LEAKY);
        node_dots_k<<<dim3((unsigned)((ec + 3) / 4)), blk, 0, stream>>>(
            hp, W_e2 + 128, nullptr, pe + base, nullptr, ec);
    }
    hipMemsetAsync(m_u, 0, (size_t)N * 4, stream);
    hipMemsetAsync(sden, 0, (size_t)N * 4, stream);
    edge_lgc_k<<<gEdge, blk, 0, stream>>>(pd, pe, b_e2, dst, lg, m_u, E);
    edge_exp_k<<<gEdge, blk, 0, stream>>>(lg, m_u, sden, dst, E);
    // pass B: recompute he1 chunk, scatter a*he1 into c; then c = c@W_et + b_et
    // (valid since softmax weights sum to 1 per node)
    hipMemsetAsync(c, 0, (size_t)N * 128 * 4, stream);
    for (int base = 0; base < E; base += Ecap) {
        const int ec = (E - base) < Ecap ? (E - base) : Ecap;
        gemm_k<<<g64(ec), blk, 0, stream>>>(
            atom, bond + (size_t)base * 12, src + base, W_e1, b_e1, hp,
            ec, 86, 74, ACT_LEAKY);
        scatter_c_k<<<dim3((unsigned)(((long long)ec * 64 + 255) / 256)), blk, 0, stream>>>(
            hp, lg + base, sden, dst + base, c, ec);
    }
    gemm_k<<<g64(N), blk, 0, stream>>>(
        c, nullptr, nullptr, W_et, b_et, c, N, 128, 128, ACT_NONE);
    run_gru(g0_Wih, g0_bih, g0_Whh, g0_bhh);

    // ---------------- 11 GNN layers ----------------
    for (int l = 0; l < L; ++l) {
        node_dots_k<<<gWave4N, blk, 0, stream>>>(
            h, Wpe + (size_t)l * 256, Wpe + (size_t)l * 256 + 128, pd, ps, N);
        gemm_k<<<g64(N), blk, 0, stream>>>(
            h, nullptr, nullptr, Wpn + (size_t)l * 16384, bpn + (size_t)l * 128,
            hp, N, 128, 128, ACT_NONE);
        layer_gather_k<<<gWave4N, blk, 0, stream>>>(
            rp, eidx, src, pd, ps, bpe + l, hp, c, N);
        run_gru(gWih + (size_t)l * 49152, gbih + (size_t)l * 384,
                gWhh + (size_t)l * 49152, gbhh + (size_t)l * 384);
    }

    // ---------------- readout ----------------
    gemm_k<<<g64(N), blk, 0, stream>>>(
        h, nullptr, nullptr, Wr1, br1, c, N, 128, 128, ACT_RELU);
    gemm_k<<<g64(N), blk, 0, stream>>>(
        c, nullptr, nullptr, Wr2, br2, hp, N, 128, 128, ACT_NONE);
    hipMemsetAsync(out, 0, (size_t)G * 128 * 4, stream);
    hipMemsetAsync(cnts, 0, (size_t)G * 4, stream);
    readout_scatter_k<<<gWave4N, blk, 0, stream>>>(hp, ngid, out, cnts, N);
    readout_div_k<<<dim3((unsigned)((G * 128 + 255) / 256)), blk, 0, stream>>>(out, cnts, G);

    (void)n_in;
}